// Round 5
// baseline (59779.144 us; speedup 1.0000x reference)
//
#include <hip/hip_runtime.h>

typedef _Float16 f16;
typedef _Float16 f16x2 __attribute__((ext_vector_type(2)));
typedef _Float16 f16x4 __attribute__((ext_vector_type(4)));
typedef _Float16 f16x8 __attribute__((ext_vector_type(8)));
typedef float    f32x4 __attribute__((ext_vector_type(4)));

static __device__ __forceinline__ float dot4(uint4 w, uint4 h, float acc) {
    acc = __builtin_amdgcn_fdot2(__builtin_bit_cast(f16x2, w.x), __builtin_bit_cast(f16x2, h.x), acc, false);
    acc = __builtin_amdgcn_fdot2(__builtin_bit_cast(f16x2, w.y), __builtin_bit_cast(f16x2, h.y), acc, false);
    acc = __builtin_amdgcn_fdot2(__builtin_bit_cast(f16x2, w.z), __builtin_bit_cast(f16x2, h.z), acc, false);
    acc = __builtin_amdgcn_fdot2(__builtin_bit_cast(f16x2, w.w), __builtin_bit_cast(f16x2, h.w), acc, false);
    return acc;
}

static __device__ __forceinline__ float dppx1(float v) {
    int r = __builtin_amdgcn_mov_dpp(__builtin_bit_cast(int, v), 0xB1, 0xF, 0xF, true); // lane^1
    return __builtin_bit_cast(float, r);
}
static __device__ __forceinline__ float dppx2(float v) {
    int r = __builtin_amdgcn_mov_dpp(__builtin_bit_cast(int, v), 0x4E, 0xF, 0xF, true); // lane^2
    return __builtin_bit_cast(float, r);
}

// ---------------- Phase 0: convert W_ih, W_hh to f16 ----------------
__global__ __launch_bounds__(256) void cvt_w(const float4* __restrict__ wih4,
                                             const float4* __restrict__ whh4,
                                             f16x4* __restrict__ wih16,
                                             f16x4* __restrict__ whh16) {
    int idx = blockIdx.x * 256 + threadIdx.x;   // 98304 total float4s
    if (idx < 32768) {
        float4 v = wih4[idx];
        wih16[idx] = (f16x4){(f16)v.x, (f16)v.y, (f16)v.z, (f16)v.w};
    } else if (idx < 98304) {
        int k = idx - 32768;
        float4 v = whh4[k];
        whh16[k] = (f16x4){(f16)v.x, (f16)v.y, (f16)v.z, (f16)v.w};
    }
}

// ---------------- Phase 1: xp = x @ W_ih^T + (b_ih + b_hh), f16 out ----------------
__global__ __launch_bounds__(256) void gemm_xp(const float* __restrict__ x,
                                               const f16* __restrict__ wih,
                                               const float* __restrict__ bih,
                                               const float* __restrict__ bhh,
                                               f16* __restrict__ xp,
                                               int tc, int t0, int L) {
    __shared__ f16 As[128][48];
    __shared__ f16 Bs[128][48];
    int tid = threadIdx.x;
    int r = tid >> 1, kh = (tid & 1) * 16;

    long mbase = (long)blockIdx.x * 128;
    int jb = blockIdx.y * 128;
    long mp = mbase + r;
    int n = (int)(mp / tc);
    int trel = (int)(mp - (long)n * tc);
    const float* xrow = x + ((long)n * L + t0 + trel) * 256 + kh;
    const f16* wrow = wih + (jb + r) * 256 + kh;

    int w = tid >> 6, l = tid & 63, lr = l & 15, lk = l >> 4;
    int wm = w & 1, wn = w >> 1;

    f32x4 acc[4][4] = {};

    for (int kk = 0; kk < 256; kk += 32) {
        float4 a0 = *(const float4*)(xrow + kk);
        float4 a1 = *(const float4*)(xrow + kk + 4);
        float4 a2 = *(const float4*)(xrow + kk + 8);
        float4 a3 = *(const float4*)(xrow + kk + 12);
        uint4  b0 = *(const uint4*)(wrow + kk);
        uint4  b1 = *(const uint4*)(wrow + kk + 8);
        f16x8 ca = {(f16)a0.x,(f16)a0.y,(f16)a0.z,(f16)a0.w,(f16)a1.x,(f16)a1.y,(f16)a1.z,(f16)a1.w};
        f16x8 cb = {(f16)a2.x,(f16)a2.y,(f16)a2.z,(f16)a2.w,(f16)a3.x,(f16)a3.y,(f16)a3.z,(f16)a3.w};
        __syncthreads();
        *(f16x8*)&As[r][kh]     = ca;
        *(f16x8*)&As[r][kh + 8] = cb;
        *(uint4*)&Bs[r][kh]     = b0;
        *(uint4*)&Bs[r][kh + 8] = b1;
        __syncthreads();

        uint4 af[4], bf[4];
#pragma unroll
        for (int mi = 0; mi < 4; ++mi) af[mi] = *(const uint4*)&As[wm * 64 + mi * 16 + lr][lk * 8];
#pragma unroll
        for (int ni = 0; ni < 4; ++ni) bf[ni] = *(const uint4*)&Bs[wn * 64 + ni * 16 + lr][lk * 8];
#pragma unroll
        for (int mi = 0; mi < 4; ++mi)
#pragma unroll
            for (int ni = 0; ni < 4; ++ni)
                acc[mi][ni] = __builtin_amdgcn_mfma_f32_16x16x32_f16(
                    __builtin_bit_cast(f16x8, af[mi]), __builtin_bit_cast(f16x8, bf[ni]),
                    acc[mi][ni], 0, 0, 0);
    }

#pragma unroll
    for (int ni = 0; ni < 4; ++ni) {
        int j = jb + wn * 64 + ni * 16 + lr;
        float bias = bih[j] + bhh[j];
#pragma unroll
        for (int mi = 0; mi < 4; ++mi) {
            long row = mbase + wm * 64 + mi * 16 + lk * 4;
#pragma unroll
            for (int rr = 0; rr < 4; ++rr)
                xp[(row + rr) * 512 + j] = (f16)(acc[mi][ni][rr] + bias);
        }
    }
}

// ---------------- Phase 2 (+fused phase 3): paired recurrence ----------------
// grid = 256 (2 WGs per batch row, each owns a 256-row half of W_hh),
// block = 512. Per-WG W = 256KB: 16 uint4/lane in regs (64 VGPR, fits the
// proven 128 budget) + 128KB LDS. Halves exchange 256 h-values per step via
// L2 mailboxes (release/acquire, agent scope, 2-slot parity buffering).
// Co-residency of all 256 WGs guaranteed via hipLaunchCooperativeKernel.
__global__ __launch_bounds__(512) void rnn_seq(const f16* __restrict__ whh16,
                                               const f16* __restrict__ xp,
                                               const float* __restrict__ hin,
                                               float* __restrict__ out,
                                               const float* __restrict__ wout,
                                               const float* __restrict__ bout,
                                               f16* __restrict__ mbD,
                                               int* __restrict__ mbF,
                                               int tc, int finalflag, int ytotal) {
    __shared__ uint4 WLDS[16 * 512];   // 128 KB, [chunk][tid] -> conflict-free b128
    __shared__ uint4 hbuf[2][8][5];    // own-half h, stride-5 padded (conflict-free)

    const int tid = threadIdx.x;
    const int b = blockIdx.x;
    const int n = b & 127;
    const int half = b >> 7;
    const int jbase = half << 8;
    const int pbase = jbase ^ 256;
    const int partner = b ^ 128;
    const int i = tid & 7;              // k-subgroup (8 x 32 k per half)
    const int jg = tid >> 3;            // j-group (64 x 4 rows)
    const int rowb = jbase + jg * 4;
    const int kA = jbase + i * 32;      // own-half k window
    const int kB = pbase + i * 32;      // partner-half k window

    // ---- W load: rows 0,1 (both windows) -> regs; rows 2,3 -> LDS ----
    uint4 wra[2][4], wrb[2][4];
#pragma unroll
    for (int r = 0; r < 2; ++r)
#pragma unroll
        for (int c = 0; c < 4; ++c) {
            wra[r][c] = *(const uint4*)&whh16[(long)(rowb + r) * 512 + kA + c * 8];
            wrb[r][c] = *(const uint4*)&whh16[(long)(rowb + r) * 512 + kB + c * 8];
        }
#pragma unroll
    for (int r2 = 0; r2 < 2; ++r2)
#pragma unroll
        for (int c = 0; c < 4; ++c) {
            WLDS[(r2 * 8 + c) * 512 + tid]     = *(const uint4*)&whh16[(long)(rowb + 2 + r2) * 512 + kA + c * 8];
            WLDS[(r2 * 8 + 4 + c) * 512 + tid] = *(const uint4*)&whh16[(long)(rowb + 2 + r2) * 512 + kB + c * 8];
        }

    // ---- h0 own half -> hbuf + prime mailbox slot0 (flag value 0) ----
    if (tid < 256) {
        float hv = hin[n * 512 + jbase + tid];
        int g = tid >> 5, ch = (tid >> 3) & 3, pos = tid & 7;
        ((f16*)&hbuf[0][0][0])[(g * 5 + ch) * 8 + pos] = (f16)hv;
        mbD[(b * 2 + 0) * 256 + tid] = (f16)hv;
    }
    __threadfence();
    __syncthreads();
    if (tid == 0)
        __hip_atomic_store(&mbF[(b * 2 + 0) * 16], 0, __ATOMIC_RELEASE, __HIP_MEMORY_SCOPE_AGENT);

    const int rfin = ((i & 1) << 1) | ((i >> 1) & 1);
    const int jfin = rowb + rfin;
    const int jloc = jfin - jbase;
    const int hwidx = ((jloc >> 5) * 5 + ((jloc >> 3) & 3)) * 8 + (jloc & 7);
    const f16* xpp = xp + ((long)n * tc) * 512 + jfin;
    int* pflag0 = &mbF[(partner * 2 + 0) * 16];
    int* pflag1 = &mbF[(partner * 2 + 1) * 16];

    float lasth = 0.f;
    int cur = 0;

    for (int t = 0; t < tc; ++t) {
        float xv = (float)xpp[(long)t * 512];
        const int slot = t & 1;

        // phase 1: own half (window A) — no wait needed
        uint4 hA0 = hbuf[cur][i][0], hA1 = hbuf[cur][i][1];
        uint4 hA2 = hbuf[cur][i][2], hA3 = hbuf[cur][i][3];
        float a0 = dot4(wra[0][3], hA3, dot4(wra[0][2], hA2, dot4(wra[0][1], hA1, dot4(wra[0][0], hA0, 0.f))));
        float a1 = dot4(wra[1][3], hA3, dot4(wra[1][2], hA2, dot4(wra[1][1], hA1, dot4(wra[1][0], hA0, 0.f))));
        float a2 = dot4(WLDS[3*512+tid], hA3, dot4(WLDS[2*512+tid], hA2, dot4(WLDS[1*512+tid], hA1, dot4(WLDS[0*512+tid], hA0, 0.f))));
        float a3 = dot4(WLDS[11*512+tid], hA3, dot4(WLDS[10*512+tid], hA2, dot4(WLDS[9*512+tid], hA1, dot4(WLDS[8*512+tid], hA0, 0.f))));

        // phase 2: partner half h_t (flag value == t at slot t&1)
        int* pf = slot ? pflag1 : pflag0;
        int guard = 0;
        while (__hip_atomic_load(pf, __ATOMIC_ACQUIRE, __HIP_MEMORY_SCOPE_AGENT) != t) {
            if (++guard > (1 << 27)) break;          // hang-bail (visible failure, no timeout)
            __builtin_amdgcn_s_sleep(1);
        }
        const uint4* pd = (const uint4*)&mbD[(partner * 2 + slot) * 256] + i * 4;
        uint4 hB0 = pd[0], hB1 = pd[1], hB2 = pd[2], hB3 = pd[3];
        a0 = dot4(wrb[0][3], hB3, dot4(wrb[0][2], hB2, dot4(wrb[0][1], hB1, dot4(wrb[0][0], hB0, a0))));
        a1 = dot4(wrb[1][3], hB3, dot4(wrb[1][2], hB2, dot4(wrb[1][1], hB1, dot4(wrb[1][0], hB0, a1))));
        a2 = dot4(WLDS[7*512+tid], hB3, dot4(WLDS[6*512+tid], hB2, dot4(WLDS[5*512+tid], hB1, dot4(WLDS[4*512+tid], hB0, a2))));
        a3 = dot4(WLDS[15*512+tid], hB3, dot4(WLDS[14*512+tid], hB2, dot4(WLDS[13*512+tid], hB1, dot4(WLDS[12*512+tid], hB0, a3))));

        // reduce over 8 k-lanes: xor1, xor2 (DPP), xor4 (shfl)
        float A0 = ((i & 1) ? a2 : a0) + dppx1((i & 1) ? a0 : a2);
        float A1 = ((i & 1) ? a3 : a1) + dppx1((i & 1) ? a1 : a3);
        float B  = ((i & 2) ? A1 : A0) + dppx2((i & 2) ? A0 : A1);
        B += __shfl_xor(B, 4);

        float pre = B + xv;
        pre = fminf(fmaxf(pre, -20.f), 20.f);
        float e = __expf(2.f * pre);
        float hn = 1.f - 2.f / (e + 1.f);        // tanh
        lasth = hn;
        if (i < 4) {
            ((f16*)&hbuf[cur ^ 1][0][0])[hwidx] = (f16)hn;   // local next-step h
        } else {
            mbD[(b * 2 + ((t + 1) & 1)) * 256 + jloc] = (f16)hn;  // post to partner
        }
        __threadfence();
        __syncthreads();
        if (tid == 0)
            __hip_atomic_store(&mbF[(b * 2 + ((t + 1) & 1)) * 16], t + 1,
                               __ATOMIC_RELEASE, __HIP_MEMORY_SCOPE_AGENT);
        cur ^= 1;
    }

    out[ytotal + n * 512 + jfin] = lasth;    // h-state (chunk handoff / final h)

    if (finalflag) {
        // assemble full h_tc: own half + partner's final post
        const int slot = tc & 1;
        int* pf = slot ? pflag1 : pflag0;
        int guard = 0;
        while (__hip_atomic_load(pf, __ATOMIC_ACQUIRE, __HIP_MEMORY_SCOPE_AGENT) != tc) {
            if (++guard > (1 << 27)) break;
            __builtin_amdgcn_s_sleep(1);
        }
        float* hf = (float*)WLDS;            // reuse W LDS (512 floats)
        hf[jfin] = lasth;
        if (tid < 256)
            hf[pbase + tid] = (float)mbD[(partner * 2 + slot) * 256 + tid];
        __syncthreads();
        if (tid < 256) {
            int jy = jbase + tid;
            float acc = bout[jy];
            const float* wrp = wout + (long)jy * 512;
#pragma unroll 4
            for (int k = 0; k < 512; k += 8) {
                float4 w0 = *(const float4*)(wrp + k);
                float4 w1 = *(const float4*)(wrp + k + 4);
                float4 g0 = *(const float4*)(hf + k);
                float4 g1 = *(const float4*)(hf + k + 4);
                acc = fmaf(w0.x, g0.x, acc); acc = fmaf(w0.y, g0.y, acc);
                acc = fmaf(w0.z, g0.z, acc); acc = fmaf(w0.w, g0.w, acc);
                acc = fmaf(w1.x, g1.x, acc); acc = fmaf(w1.y, g1.y, acc);
                acc = fmaf(w1.z, g1.z, acc); acc = fmaf(w1.w, g1.w, acc);
            }
            out[n * 512 + jy] = acc;         // y
        }
    }
}

extern "C" void kernel_launch(void* const* d_in, const int* in_sizes, int n_in,
                              void* d_out, int out_size, void* d_ws, size_t ws_size,
                              hipStream_t stream) {
    const float* x    = (const float*)d_in[0];
    const float* h0   = (const float*)d_in[1];
    const float* wih  = (const float*)d_in[2];
    const float* whh  = (const float*)d_in[3];
    const float* bih  = (const float*)d_in[4];
    const float* bhh  = (const float*)d_in[5];
    const float* wout = (const float*)d_in[6];
    const float* bout = (const float*)d_in[7];
    float* out = (float*)d_out;

    int N = in_sizes[1] / 512;                          // 128
    int L = (int)((long)in_sizes[0] / ((long)N * 256)); // 1024
    int ytotal = N * 512;

    char* ws = (char*)d_ws;
    int* mbF   = (int*)ws;                  //      0 .. 32768   (256*2 flags, 64B stride)
    f16* mbD   = (f16*)(ws + 32768);        //  32768 .. 294912  (256*2*256 f16)
    f16* whh16 = (f16*)(ws + 294912);       // 294912 .. 819200
    f16* wih16 = (f16*)(ws + 819200);       // 819200 .. 1081344
    f16* xp    = (f16*)(ws + 1081344);
    long per_t = (long)N * 512 * 2;
    long cap = (ws_size > 1081344) ? (long)(ws_size - 1081344) : 0;
    long Tc = cap / per_t;
    if (Tc > L) Tc = L;
    if (Tc < 1) Tc = 1;

    cvt_w<<<384, 256, 0, stream>>>((const float4*)wih, (const float4*)whh,
                                   (f16x4*)wih16, (f16x4*)whh16);

    for (int t0 = 0; t0 < L;) {
        int tc = (int)((L - t0 < Tc) ? (L - t0) : Tc);
        gemm_xp<<<dim3(tc, 4), 256, 0, stream>>>(x, wih16, bih, bhh, xp, tc, t0, L);
        const float* hsrc = (t0 == 0) ? h0 : (const float*)(out + ytotal);
        int fin = (t0 + tc == L) ? 1 : 0;

        const f16* whh16c = whh16;
        const f16* xpc = xp;
        void* args[] = { (void*)&whh16c, (void*)&xpc, (void*)&hsrc, (void*)&out,
                         (void*)&wout, (void*)&bout, (void*)&mbD, (void*)&mbF,
                         (void*)&tc, (void*)&fin, (void*)&ytotal };
        hipLaunchCooperativeKernel((const void*)rnn_seq, dim3(256), dim3(512),
                                   args, 0, stream);
        t0 += tc;
    }
}

// Round 6
// 3045.673 us; speedup vs baseline: 19.6276x; 19.6276x over previous
//
#include <hip/hip_runtime.h>

typedef _Float16 f16;
typedef _Float16 f16x2 __attribute__((ext_vector_type(2)));
typedef _Float16 f16x4 __attribute__((ext_vector_type(4)));
typedef _Float16 f16x8 __attribute__((ext_vector_type(8)));
typedef float    f32x4 __attribute__((ext_vector_type(4)));

static __device__ __forceinline__ float dot4(uint4 w, uint4 h, float acc) {
    acc = __builtin_amdgcn_fdot2(__builtin_bit_cast(f16x2, w.x), __builtin_bit_cast(f16x2, h.x), acc, false);
    acc = __builtin_amdgcn_fdot2(__builtin_bit_cast(f16x2, w.y), __builtin_bit_cast(f16x2, h.y), acc, false);
    acc = __builtin_amdgcn_fdot2(__builtin_bit_cast(f16x2, w.z), __builtin_bit_cast(f16x2, h.z), acc, false);
    acc = __builtin_amdgcn_fdot2(__builtin_bit_cast(f16x2, w.w), __builtin_bit_cast(f16x2, h.w), acc, false);
    return acc;
}

static __device__ __forceinline__ float dppx1(float v) {
    int r = __builtin_amdgcn_mov_dpp(__builtin_bit_cast(int, v), 0xB1, 0xF, 0xF, true); // lane^1
    return __builtin_bit_cast(float, r);
}
static __device__ __forceinline__ float dppx2(float v) {
    int r = __builtin_amdgcn_mov_dpp(__builtin_bit_cast(int, v), 0x4E, 0xF, 0xF, true); // lane^2
    return __builtin_bit_cast(float, r);
}

// ---------------- Phase 0: convert W_ih, W_hh to f16 ----------------
__global__ __launch_bounds__(256) void cvt_w(const float4* __restrict__ wih4,
                                             const float4* __restrict__ whh4,
                                             f16x4* __restrict__ wih16,
                                             f16x4* __restrict__ whh16) {
    int idx = blockIdx.x * 256 + threadIdx.x;   // 98304 total float4s
    if (idx < 32768) {
        float4 v = wih4[idx];
        wih16[idx] = (f16x4){(f16)v.x, (f16)v.y, (f16)v.z, (f16)v.w};
    } else if (idx < 98304) {
        int k = idx - 32768;
        float4 v = whh4[k];
        whh16[k] = (f16x4){(f16)v.x, (f16)v.y, (f16)v.z, (f16)v.w};
    }
}

// ---------------- Phase 1: xp = x @ W_ih^T + (b_ih + b_hh), f16 out ----------------
__global__ __launch_bounds__(256) void gemm_xp(const float* __restrict__ x,
                                               const f16* __restrict__ wih,
                                               const float* __restrict__ bih,
                                               const float* __restrict__ bhh,
                                               f16* __restrict__ xp,
                                               int tc, int t0, int L) {
    __shared__ f16 As[128][48];
    __shared__ f16 Bs[128][48];
    int tid = threadIdx.x;
    int r = tid >> 1, kh = (tid & 1) * 16;

    long mbase = (long)blockIdx.x * 128;
    int jb = blockIdx.y * 128;
    long mp = mbase + r;
    int n = (int)(mp / tc);
    int trel = (int)(mp - (long)n * tc);
    const float* xrow = x + ((long)n * L + t0 + trel) * 256 + kh;
    const f16* wrow = wih + (jb + r) * 256 + kh;

    int w = tid >> 6, l = tid & 63, lr = l & 15, lk = l >> 4;
    int wm = w & 1, wn = w >> 1;

    f32x4 acc[4][4] = {};

    for (int kk = 0; kk < 256; kk += 32) {
        float4 a0 = *(const float4*)(xrow + kk);
        float4 a1 = *(const float4*)(xrow + kk + 4);
        float4 a2 = *(const float4*)(xrow + kk + 8);
        float4 a3 = *(const float4*)(xrow + kk + 12);
        uint4  b0 = *(const uint4*)(wrow + kk);
        uint4  b1 = *(const uint4*)(wrow + kk + 8);
        f16x8 ca = {(f16)a0.x,(f16)a0.y,(f16)a0.z,(f16)a0.w,(f16)a1.x,(f16)a1.y,(f16)a1.z,(f16)a1.w};
        f16x8 cb = {(f16)a2.x,(f16)a2.y,(f16)a2.z,(f16)a2.w,(f16)a3.x,(f16)a3.y,(f16)a3.z,(f16)a3.w};
        __syncthreads();
        *(f16x8*)&As[r][kh]     = ca;
        *(f16x8*)&As[r][kh + 8] = cb;
        *(uint4*)&Bs[r][kh]     = b0;
        *(uint4*)&Bs[r][kh + 8] = b1;
        __syncthreads();

        uint4 af[4], bf[4];
#pragma unroll
        for (int mi = 0; mi < 4; ++mi) af[mi] = *(const uint4*)&As[wm * 64 + mi * 16 + lr][lk * 8];
#pragma unroll
        for (int ni = 0; ni < 4; ++ni) bf[ni] = *(const uint4*)&Bs[wn * 64 + ni * 16 + lr][lk * 8];
#pragma unroll
        for (int mi = 0; mi < 4; ++mi)
#pragma unroll
            for (int ni = 0; ni < 4; ++ni)
                acc[mi][ni] = __builtin_amdgcn_mfma_f32_16x16x32_f16(
                    __builtin_bit_cast(f16x8, af[mi]), __builtin_bit_cast(f16x8, bf[ni]),
                    acc[mi][ni], 0, 0, 0);
    }

#pragma unroll
    for (int ni = 0; ni < 4; ++ni) {
        int j = jb + wn * 64 + ni * 16 + lr;
        float bias = bih[j] + bhh[j];
#pragma unroll
        for (int mi = 0; mi < 4; ++mi) {
            long row = mbase + wm * 64 + mi * 16 + lk * 4;
#pragma unroll
            for (int rr = 0; rr < 4; ++rr)
                xp[(row + rr) * 512 + j] = (f16)(acc[mi][ni][rr] + bias);
        }
    }
}

// ---------------- Phase 2 (+fused phase 3): the recurrence ----------------
// grid = N (128), block = 256 (4 waves, 1 wave/SIMD -> 512-VGPR budget).
// Per lane: 16 rows x 64 k of W_hh. Chunks 0..5 in regs (384 VGPRs),
// chunks 6,7 in 128 KB LDS (tid-contiguous, conflict-free). W never
// touches L2 after the initial load -> breaks the 1.5ms L2-stream ceiling.
__global__ __launch_bounds__(256, 1) void rnn_seq(const f16* __restrict__ whh16,
                                                  const f16* __restrict__ xp,
                                                  const float* __restrict__ hin,
                                                  float* __restrict__ out,
                                                  const float* __restrict__ wout,
                                                  const float* __restrict__ bout,
                                                  int tc, int finalflag, int ytotal) {
    __shared__ uint4 WL[8192];     // 128 KB: [(r*2+cc)*256 + tid]
    __shared__ uint4 hb[2][64];    // h, XOR-chunk swizzled: slot = g*8 + (c^g)

    const int tid = threadIdx.x;
    const int n = blockIdx.x;
    const int i  = tid & 7;        // k-group: k in [i*64, i*64+64)
    const int jg = tid >> 3;       // j-group: rows [jg*16, jg*16+16)

    // ---- W load: per lane 16 rows x 8 chunks; 6 -> regs, 2 -> LDS ----
    uint4 wr[16][6];
    const f16* wbase = whh16 + (long)(jg * 16) * 512 + i * 64;
#pragma unroll
    for (int r = 0; r < 16; ++r) {
        const uint4* p = (const uint4*)(wbase + (long)r * 512);
#pragma unroll
        for (int c = 0; c < 6; ++c) wr[r][c] = p[c];
        WL[(r * 2 + 0) * 256 + tid] = p[6];
        WL[(r * 2 + 1) * 256 + tid] = p[7];
    }

    // ---- h0 into swizzled layout (2 elements per thread) ----
    f16* hb0 = (f16*)&hb[0][0];
#pragma unroll
    for (int e = 0; e < 2; ++e) {
        int j = tid * 2 + e;
        int g = j >> 6, c = (j >> 3) & 7, p = j & 7;
        hb0[(g * 8 + (c ^ g)) * 8 + p] = (f16)hin[n * 512 + j];
    }
    __syncthreads();

    // final row ownership after 3-stage reduce: rows {j0, j0+1}
    const int jr0 = 8 * (i & 1) + 4 * ((i >> 1) & 1) + 2 * ((i >> 2) & 1);
    const int j0 = jg * 16 + jr0;
    const int wg0 = j0 >> 6, wc0 = (j0 >> 3) & 7, wp0 = j0 & 7;
    const int hwidx = (wg0 * 8 + (wc0 ^ wg0)) * 8 + wp0;   // even -> 4B aligned
    const f16* xpp = xp + ((long)n * tc) * 512 + j0;

    float h0f = 0.f, h1f = 0.f;
    int cur = 0;

    for (int t = 0; t < tc; ++t) {
        unsigned xv2 = *(const unsigned*)(xpp + (long)t * 512);  // issue early (f16x2)

        const uint4* hc = &hb[cur][i * 8];
        float a[16];

        // phase 1: chunks 0..3 (regs)
        uint4 h0 = hc[0 ^ i], h1 = hc[1 ^ i], h2 = hc[2 ^ i], h3 = hc[3 ^ i];
#pragma unroll
        for (int r = 0; r < 16; ++r)
            a[r] = dot4(wr[r][3], h3, dot4(wr[r][2], h2, dot4(wr[r][1], h1, dot4(wr[r][0], h0, 0.f))));
        // phase 2: chunks 4,5 (regs) + 6,7 (LDS)
        h0 = hc[4 ^ i]; h1 = hc[5 ^ i]; h2 = hc[6 ^ i]; h3 = hc[7 ^ i];
#pragma unroll
        for (int r = 0; r < 16; ++r) {
            float v = dot4(wr[r][5], h1, dot4(wr[r][4], h0, a[r]));
            v = dot4(WL[(r * 2 + 0) * 256 + tid], h2, v);
            a[r] = dot4(WL[(r * 2 + 1) * 256 + tid], h3, v);
        }

        // reduce over 8 k-lanes: xor1, xor2 (DPP), xor4 (shfl)
#pragma unroll
        for (int s = 0; s < 8; ++s) {
            float lo = a[s], hi = a[s + 8];
            float keep = (i & 1) ? hi : lo, send = (i & 1) ? lo : hi;
            a[s] = keep + dppx1(send);
        }
#pragma unroll
        for (int s = 0; s < 4; ++s) {
            float lo = a[s], hi = a[s + 4];
            float keep = (i & 2) ? hi : lo, send = (i & 2) ? lo : hi;
            a[s] = keep + dppx2(send);
        }
#pragma unroll
        for (int s = 0; s < 2; ++s) {
            float lo = a[s], hi = a[s + 2];
            float keep = (i & 4) ? hi : lo, send = (i & 4) ? lo : hi;
            a[s] = keep + __shfl_xor(send, 4);
        }

        f16x2 xv = __builtin_bit_cast(f16x2, xv2);
        float pre0 = a[0] + (float)xv.x;
        float pre1 = a[1] + (float)xv.y;
        pre0 = fminf(fmaxf(pre0, -20.f), 20.f);
        pre1 = fminf(fmaxf(pre1, -20.f), 20.f);
        h0f = 1.f - 2.f / (__expf(2.f * pre0) + 1.f);
        h1f = 1.f - 2.f / (__expf(2.f * pre1) + 1.f);
        f16x2 hx = {(f16)h0f, (f16)h1f};
        *(f16x2*)&((f16*)&hb[cur ^ 1][0])[hwidx] = hx;
        __syncthreads();
        cur ^= 1;
    }

    out[ytotal + n * 512 + j0]     = h0f;   // h-state (chunk handoff / final h)
    out[ytotal + n * 512 + j0 + 1] = h1f;

    if (finalflag) {
        float* hf = (float*)WL;             // reuse W LDS (512 floats)
        hf[j0]     = h0f;
        hf[j0 + 1] = h1f;
        __syncthreads();
#pragma unroll
        for (int e = 0; e < 2; ++e) {
            int jy = tid + e * 256;
            float acc = bout[jy];
            const float* wrp = wout + (long)jy * 512;
#pragma unroll 4
            for (int k = 0; k < 512; k += 8) {
                float4 w0 = *(const float4*)(wrp + k);
                float4 w1 = *(const float4*)(wrp + k + 4);
                float4 g0 = *(const float4*)(hf + k);
                float4 g1 = *(const float4*)(hf + k + 4);
                acc = fmaf(w0.x, g0.x, acc); acc = fmaf(w0.y, g0.y, acc);
                acc = fmaf(w0.z, g0.z, acc); acc = fmaf(w0.w, g0.w, acc);
                acc = fmaf(w1.x, g1.x, acc); acc = fmaf(w1.y, g1.y, acc);
                acc = fmaf(w1.z, g1.z, acc); acc = fmaf(w1.w, g1.w, acc);
            }
            out[n * 512 + jy] = acc;        // y
        }
    }
}

extern "C" void kernel_launch(void* const* d_in, const int* in_sizes, int n_in,
                              void* d_out, int out_size, void* d_ws, size_t ws_size,
                              hipStream_t stream) {
    const float* x    = (const float*)d_in[0];
    const float* h0   = (const float*)d_in[1];
    const float* wih  = (const float*)d_in[2];
    const float* whh  = (const float*)d_in[3];
    const float* bih  = (const float*)d_in[4];
    const float* bhh  = (const float*)d_in[5];
    const float* wout = (const float*)d_in[6];
    const float* bout = (const float*)d_in[7];
    float* out = (float*)d_out;

    int N = in_sizes[1] / 512;                          // 128
    int L = (int)((long)in_sizes[0] / ((long)N * 256)); // 1024
    int ytotal = N * 512;

    char* ws = (char*)d_ws;
    f16* whh16 = (f16*)ws;                 // 524288 B
    f16* wih16 = (f16*)(ws + 524288);      // 262144 B
    f16* xp    = (f16*)(ws + 786432);
    long per_t = (long)N * 512 * 2;
    long cap = (ws_size > 786432) ? (long)(ws_size - 786432) : 0;
    long Tc = cap / per_t;
    if (Tc > L) Tc = L;
    if (Tc < 1) Tc = 1;

    cvt_w<<<384, 256, 0, stream>>>((const float4*)wih, (const float4*)whh,
                                   (f16x4*)wih16, (f16x4*)whh16);

    for (int t0 = 0; t0 < L;) {
        int tc = (int)((L - t0 < Tc) ? (L - t0) : Tc);
        gemm_xp<<<dim3(tc, 4), 256, 0, stream>>>(x, wih16, bih, bhh, xp, tc, t0, L);
        const float* hsrc = (t0 == 0) ? h0 : (const float*)(out + ytotal);
        int fin = (t0 + tc == L) ? 1 : 0;
        rnn_seq<<<N, 256, 0, stream>>>(whh16, xp, hsrc, out, wout, bout, tc, fin, ytotal);
        t0 += tc;
    }
}

// Round 7
// 1778.379 us; speedup vs baseline: 33.6144x; 1.7126x over previous
//
#include <hip/hip_runtime.h>

typedef _Float16 f16;
typedef _Float16 f16x2 __attribute__((ext_vector_type(2)));
typedef _Float16 f16x4 __attribute__((ext_vector_type(4)));
typedef _Float16 f16x8 __attribute__((ext_vector_type(8)));
typedef float    f32x4 __attribute__((ext_vector_type(4)));

static __device__ __forceinline__ float dot4(uint4 w, uint4 h, float acc) {
    acc = __builtin_amdgcn_fdot2(__builtin_bit_cast(f16x2, w.x), __builtin_bit_cast(f16x2, h.x), acc, false);
    acc = __builtin_amdgcn_fdot2(__builtin_bit_cast(f16x2, w.y), __builtin_bit_cast(f16x2, h.y), acc, false);
    acc = __builtin_amdgcn_fdot2(__builtin_bit_cast(f16x2, w.z), __builtin_bit_cast(f16x2, h.z), acc, false);
    acc = __builtin_amdgcn_fdot2(__builtin_bit_cast(f16x2, w.w), __builtin_bit_cast(f16x2, h.w), acc, false);
    return acc;
}

static __device__ __forceinline__ float dppx1(float v) {
    int r = __builtin_amdgcn_mov_dpp(__builtin_bit_cast(int, v), 0xB1, 0xF, 0xF, true); // lane^1
    return __builtin_bit_cast(float, r);
}
static __device__ __forceinline__ float dppx2(float v) {
    int r = __builtin_amdgcn_mov_dpp(__builtin_bit_cast(int, v), 0x4E, 0xF, 0xF, true); // lane^2
    return __builtin_bit_cast(float, r);
}

// ---------------- Phase 0: convert W_ih, W_hh to f16 ----------------
__global__ __launch_bounds__(256) void cvt_w(const float4* __restrict__ wih4,
                                             const float4* __restrict__ whh4,
                                             f16x4* __restrict__ wih16,
                                             f16x4* __restrict__ whh16) {
    int idx = blockIdx.x * 256 + threadIdx.x;   // 98304 total float4s
    if (idx < 32768) {
        float4 v = wih4[idx];
        wih16[idx] = (f16x4){(f16)v.x, (f16)v.y, (f16)v.z, (f16)v.w};
    } else if (idx < 98304) {
        int k = idx - 32768;
        float4 v = whh4[k];
        whh16[k] = (f16x4){(f16)v.x, (f16)v.y, (f16)v.z, (f16)v.w};
    }
}

// ---------------- Phase 1: xp = x @ W_ih^T + (b_ih + b_hh), f16 out ----------------
__global__ __launch_bounds__(256) void gemm_xp(const float* __restrict__ x,
                                               const f16* __restrict__ wih,
                                               const float* __restrict__ bih,
                                               const float* __restrict__ bhh,
                                               f16* __restrict__ xp,
                                               int tc, int t0, int L) {
    __shared__ f16 As[128][48];
    __shared__ f16 Bs[128][48];
    int tid = threadIdx.x;
    int r = tid >> 1, kh = (tid & 1) * 16;

    long mbase = (long)blockIdx.x * 128;
    int jb = blockIdx.y * 128;
    long mp = mbase + r;
    int n = (int)(mp / tc);
    int trel = (int)(mp - (long)n * tc);
    const float* xrow = x + ((long)n * L + t0 + trel) * 256 + kh;
    const f16* wrow = wih + (jb + r) * 256 + kh;

    int w = tid >> 6, l = tid & 63, lr = l & 15, lk = l >> 4;
    int wm = w & 1, wn = w >> 1;

    f32x4 acc[4][4] = {};

    for (int kk = 0; kk < 256; kk += 32) {
        float4 a0 = *(const float4*)(xrow + kk);
        float4 a1 = *(const float4*)(xrow + kk + 4);
        float4 a2 = *(const float4*)(xrow + kk + 8);
        float4 a3 = *(const float4*)(xrow + kk + 12);
        uint4  b0 = *(const uint4*)(wrow + kk);
        uint4  b1 = *(const uint4*)(wrow + kk + 8);
        f16x8 ca = {(f16)a0.x,(f16)a0.y,(f16)a0.z,(f16)a0.w,(f16)a1.x,(f16)a1.y,(f16)a1.z,(f16)a1.w};
        f16x8 cb = {(f16)a2.x,(f16)a2.y,(f16)a2.z,(f16)a2.w,(f16)a3.x,(f16)a3.y,(f16)a3.z,(f16)a3.w};
        __syncthreads();
        *(f16x8*)&As[r][kh]     = ca;
        *(f16x8*)&As[r][kh + 8] = cb;
        *(uint4*)&Bs[r][kh]     = b0;
        *(uint4*)&Bs[r][kh + 8] = b1;
        __syncthreads();

        uint4 af[4], bf[4];
#pragma unroll
        for (int mi = 0; mi < 4; ++mi) af[mi] = *(const uint4*)&As[wm * 64 + mi * 16 + lr][lk * 8];
#pragma unroll
        for (int ni = 0; ni < 4; ++ni) bf[ni] = *(const uint4*)&Bs[wn * 64 + ni * 16 + lr][lk * 8];
#pragma unroll
        for (int mi = 0; mi < 4; ++mi)
#pragma unroll
            for (int ni = 0; ni < 4; ++ni)
                acc[mi][ni] = __builtin_amdgcn_mfma_f32_16x16x32_f16(
                    __builtin_bit_cast(f16x8, af[mi]), __builtin_bit_cast(f16x8, bf[ni]),
                    acc[mi][ni], 0, 0, 0);
    }

#pragma unroll
    for (int ni = 0; ni < 4; ++ni) {
        int j = jb + wn * 64 + ni * 16 + lr;
        float bias = bih[j] + bhh[j];
#pragma unroll
        for (int mi = 0; mi < 4; ++mi) {
            long row = mbase + wm * 64 + mi * 16 + lk * 4;
#pragma unroll
            for (int rr = 0; rr < 4; ++rr)
                xp[(row + rr) * 512 + j] = (f16)(acc[mi][ni][rr] + bias);
        }
    }
}

// ---------------- Phase 2 (+fused phase 3): the recurrence ----------------
// grid = N (128), block = 512 (8 waves, 2/SIMD -> 256-VGPR cap via (512,1)).
// Per lane: 8 rows x 64 k of W_hh = 1KB. Chunks 0..5 in regs (192 VGPRs,
// inside the ~236 the allocator granted in R6), chunks 6,7 in 128 KB LDS
// (tid-contiguous, measured conflict-free in R6). 2 waves/SIMD restore
// latency hiding that R6's 1-wave config lacked.
__global__ __launch_bounds__(512, 1) void rnn_seq(const f16* __restrict__ whh16,
                                                  const f16* __restrict__ xp,
                                                  const float* __restrict__ hin,
                                                  float* __restrict__ out,
                                                  const float* __restrict__ wout,
                                                  const float* __restrict__ bout,
                                                  int tc, int finalflag, int ytotal) {
    __shared__ uint4 WL[16 * 512];  // 128 KB: [(r*2+cc)*512 + tid]
    __shared__ uint4 hb[2][64];     // h, XOR-chunk swizzled: slot = g*8 + (c^g)

    const int tid = threadIdx.x;
    const int n = blockIdx.x;
    const int i  = tid & 7;         // k-group: k in [i*64, i*64+64)
    const int jg = tid >> 3;        // j-group: rows [jg*8, jg*8+8)

    // ---- W load: per lane 8 rows x 8 chunks; 6 -> regs, 2 -> LDS ----
    uint4 wr[8][6];
    const f16* wbase = whh16 + (long)(jg * 8) * 512 + i * 64;
#pragma unroll
    for (int r = 0; r < 8; ++r) {
        const uint4* p = (const uint4*)(wbase + (long)r * 512);
#pragma unroll
        for (int c = 0; c < 6; ++c) wr[r][c] = p[c];
        WL[(r * 2 + 0) * 512 + tid] = p[6];
        WL[(r * 2 + 1) * 512 + tid] = p[7];
    }

    // ---- h0 into swizzled layout (1 element per thread) ----
    {
        int j = tid;
        int g = j >> 6, c = (j >> 3) & 7, p = j & 7;
        ((f16*)&hb[0][0])[(g * 8 + (c ^ g)) * 8 + p] = (f16)hin[n * 512 + j];
    }
    __syncthreads();

    // final row ownership after 3-stage reduce (validated in R1)
    const int jfin = jg * 8 + (((i & 1) << 2) | (i & 2) | ((i >> 2) & 1)); // bitrev3(i)
    const int wg0 = jfin >> 6, wc0 = (jfin >> 3) & 7, wp0 = jfin & 7;
    const int hwidx = (wg0 * 8 + (wc0 ^ wg0)) * 8 + wp0;
    const f16* xpp = xp + ((long)n * tc) * 512 + jfin;

    float lasth = 0.f;
    int cur = 0;

    for (int t = 0; t < tc; ++t) {
        float xv = (float)xpp[(long)t * 512];   // scalar f16, issued early

        const uint4* hc = &hb[cur][i * 8];
        float a[8];

        // phase A: chunks 0..3 (regs)
        uint4 h0 = hc[0 ^ i], h1 = hc[1 ^ i], h2 = hc[2 ^ i], h3 = hc[3 ^ i];
#pragma unroll
        for (int r = 0; r < 8; ++r)
            a[r] = dot4(wr[r][3], h3, dot4(wr[r][2], h2, dot4(wr[r][1], h1, dot4(wr[r][0], h0, 0.f))));
        // phase B: chunks 4,5 (regs) + 6,7 (LDS)
        h0 = hc[4 ^ i]; h1 = hc[5 ^ i]; h2 = hc[6 ^ i]; h3 = hc[7 ^ i];
#pragma unroll
        for (int r = 0; r < 8; ++r) {
            float v = dot4(wr[r][5], h1, dot4(wr[r][4], h0, a[r]));
            v = dot4(WL[(r * 2 + 0) * 512 + tid], h2, v);
            a[r] = dot4(WL[(r * 2 + 1) * 512 + tid], h3, v);
        }

        // reduce over 8 k-lanes: xor1, xor2 (DPP), xor4 (shfl)
#pragma unroll
        for (int s = 0; s < 4; ++s) {
            float lo = a[s], hi = a[s + 4];
            float keep = (i & 1) ? hi : lo, send = (i & 1) ? lo : hi;
            a[s] = keep + dppx1(send);
        }
#pragma unroll
        for (int s = 0; s < 2; ++s) {
            float lo = a[s], hi = a[s + 2];
            float keep = (i & 2) ? hi : lo, send = (i & 2) ? lo : hi;
            a[s] = keep + dppx2(send);
        }
        {
            float lo = a[0], hi = a[1];
            float keep = (i & 4) ? hi : lo, send = (i & 4) ? lo : hi;
            a[0] = keep + __shfl_xor(send, 4);
        }

        float pre = a[0] + xv;
        pre = fminf(fmaxf(pre, -20.f), 20.f);
        float e = __expf(2.f * pre);
        float hn = 1.f - 2.f / (e + 1.f);      // tanh
        lasth = hn;
        ((f16*)&hb[cur ^ 1][0])[hwidx] = (f16)hn;
        __syncthreads();
        cur ^= 1;
    }

    out[ytotal + n * 512 + jfin] = lasth;   // h-state (chunk handoff / final h)

    if (finalflag) {
        float* hf = (float*)WL;             // reuse W LDS (512 floats)
        hf[jfin] = lasth;
        __syncthreads();
        int jy = tid;
        float acc = bout[jy];
        const float* wrp = wout + (long)jy * 512;
#pragma unroll 4
        for (int k = 0; k < 512; k += 8) {
            float4 w0 = *(const float4*)(wrp + k);
            float4 w1 = *(const float4*)(wrp + k + 4);
            float4 g0 = *(const float4*)(hf + k);
            float4 g1 = *(const float4*)(hf + k + 4);
            acc = fmaf(w0.x, g0.x, acc); acc = fmaf(w0.y, g0.y, acc);
            acc = fmaf(w0.z, g0.z, acc); acc = fmaf(w0.w, g0.w, acc);
            acc = fmaf(w1.x, g1.x, acc); acc = fmaf(w1.y, g1.y, acc);
            acc = fmaf(w1.z, g1.z, acc); acc = fmaf(w1.w, g1.w, acc);
        }
        out[n * 512 + jy] = acc;            // y
    }
}

extern "C" void kernel_launch(void* const* d_in, const int* in_sizes, int n_in,
                              void* d_out, int out_size, void* d_ws, size_t ws_size,
                              hipStream_t stream) {
    const float* x    = (const float*)d_in[0];
    const float* h0   = (const float*)d_in[1];
    const float* wih  = (const float*)d_in[2];
    const float* whh  = (const float*)d_in[3];
    const float* bih  = (const float*)d_in[4];
    const float* bhh  = (const float*)d_in[5];
    const float* wout = (const float*)d_in[6];
    const float* bout = (const float*)d_in[7];
    float* out = (float*)d_out;

    int N = in_sizes[1] / 512;                          // 128
    int L = (int)((long)in_sizes[0] / ((long)N * 256)); // 1024
    int ytotal = N * 512;

    char* ws = (char*)d_ws;
    f16* whh16 = (f16*)ws;                 // 524288 B
    f16* wih16 = (f16*)(ws + 524288);      // 262144 B
    f16* xp    = (f16*)(ws + 786432);
    long per_t = (long)N * 512 * 2;
    long cap = (ws_size > 786432) ? (long)(ws_size - 786432) : 0;
    long Tc = cap / per_t;
    if (Tc > L) Tc = L;
    if (Tc < 1) Tc = 1;

    cvt_w<<<384, 256, 0, stream>>>((const float4*)wih, (const float4*)whh,
                                   (f16x4*)wih16, (f16x4*)whh16);

    for (int t0 = 0; t0 < L;) {
        int tc = (int)((L - t0 < Tc) ? (L - t0) : Tc);
        gemm_xp<<<dim3(tc, 4), 256, 0, stream>>>(x, wih16, bih, bhh, xp, tc, t0, L);
        const float* hsrc = (t0 == 0) ? h0 : (const float*)(out + ytotal);
        int fin = (t0 + tc == L) ? 1 : 0;
        rnn_seq<<<N, 512, 0, stream>>>(whh16, xp, hsrc, out, wout, bout, tc, fin, ytotal);
        t0 += tc;
    }
}